// Round 1
// baseline (1196.058 us; speedup 1.0000x reference)
//
#include <hip/hip_runtime.h>
#include <hip/hip_bf16.h>
#include <stdint.h>

// LinearAttention: B=4 N=8192 C=1152 H=36 D=32
// Pipeline: convert->bf16, GEMM1(qkv,+ReLU), kv-reduce, attn-normalize, GEMM2(+bias)

#define HH 36
#define DD 32
#define CC 1152
#define NB 4
#define NN 8192
#define M_TOT (NB * NN)   // 32768
#define N1 (3 * HH * DD)  // 3456
#define HD (HH * DD)      // 1152
#define HPB 6

typedef __attribute__((ext_vector_type(8))) short bf16x8;
typedef __attribute__((ext_vector_type(4))) float f32x4;

__device__ __forceinline__ uint16_t f2b(float f) {
  union { float f; uint32_t u; } v; v.f = f;
  uint32_t u = v.u;
  return (uint16_t)((u + 0x7fffu + ((u >> 16) & 1u)) >> 16);
}
__device__ __forceinline__ float uasf(uint32_t u) {
  union { uint32_t u; float f; } v; v.u = u; return v.f;
}
// unpack 8 packed bf16 (uint4) -> two f32x4
__device__ __forceinline__ void unpack8v(uint4 u, f32x4& lo, f32x4& hi) {
  lo[0] = uasf(u.x << 16); lo[1] = uasf(u.x & 0xffff0000u);
  lo[2] = uasf(u.y << 16); lo[3] = uasf(u.y & 0xffff0000u);
  hi[0] = uasf(u.z << 16); hi[1] = uasf(u.z & 0xffff0000u);
  hi[2] = uasf(u.w << 16); hi[3] = uasf(u.w & 0xffff0000u);
}

__global__ void zero_kernel(float* __restrict__ p, int n) {
  int i = blockIdx.x * blockDim.x + threadIdx.x;
  if (i < n) p[i] = 0.f;
}

__global__ void convert_kernel(const float* __restrict__ in, uint16_t* __restrict__ out, int n4) {
  int i = blockIdx.x * blockDim.x + threadIdx.x;
  if (i >= n4) return;
  float4 v = ((const float4*)in)[i];
  ushort4 o;
  o.x = f2b(v.x); o.y = f2b(v.y); o.z = f2b(v.z); o.w = f2b(v.w);
  ((ushort4*)out)[i] = o;
}

// in: [R][Cc] fp32 -> out: [Cc][R] bf16  (32x32 LDS tile transpose)
__global__ void transpose_convert_kernel(const float* __restrict__ in, uint16_t* __restrict__ out,
                                         int R, int Cc) {
  __shared__ uint16_t tile[32][33];
  int c0 = blockIdx.x * 32, r0 = blockIdx.y * 32;
  int tx = threadIdx.x & 31, ty = threadIdx.x >> 5;
#pragma unroll
  for (int i = 0; i < 4; i++) {
    int r = ty + i * 8;
    tile[r][tx] = f2b(in[(size_t)(r0 + r) * Cc + c0 + tx]);
  }
  __syncthreads();
#pragma unroll
  for (int i = 0; i < 4; i++) {
    int c = ty + i * 8;
    out[(size_t)(c0 + c) * R + r0 + tx] = tile[tx][c];
  }
}

// C[m][n] = sum_k A[m][k] * BT[n][k].  128x128 tile, BK=32, 4 waves (2x2), each 64x64.
// EPI==0: ReLU on cols < 2*HD, store bf16.  EPI==1: +bias, store fp32.
template <int EPI>
__global__ __launch_bounds__(256, 2)
void gemm_bf16_kernel(const uint16_t* __restrict__ A, const uint16_t* __restrict__ BT,
                      uint16_t* __restrict__ outb, float* __restrict__ outf,
                      const float* __restrict__ bias, int Nc, int K) {
  __shared__ uint16_t As[128][40];
  __shared__ uint16_t Bs[128][40];
  const int n0 = blockIdx.x * 128, m0 = blockIdx.y * 128;
  const int t = threadIdx.x;
  const int lane = t & 63, w = t >> 6;
  const int wr = w >> 1, wc = w & 1;
  const int l15 = lane & 15, q4 = lane >> 4;
  f32x4 acc[4][4] = {};
  const int srow = t >> 1;
  const int sseg = (t & 1) * 16;
  const uint16_t* Ap = A + (size_t)(m0 + srow) * K + sseg;
  const uint16_t* Bp = BT + (size_t)(n0 + srow) * K + sseg;
  const int aoff = q4 * 8;
  for (int k0 = 0; k0 < K; k0 += 32) {
    uint4 a0 = *(const uint4*)(Ap + k0);
    uint4 a1 = *(const uint4*)(Ap + k0 + 8);
    uint4 b0 = *(const uint4*)(Bp + k0);
    uint4 b1 = *(const uint4*)(Bp + k0 + 8);
    __syncthreads();
    *(uint4*)&As[srow][sseg] = a0;
    *(uint4*)&As[srow][sseg + 8] = a1;
    *(uint4*)&Bs[srow][sseg] = b0;
    *(uint4*)&Bs[srow][sseg + 8] = b1;
    __syncthreads();
    bf16x8 af[4], bfr[4];
#pragma unroll
    for (int i = 0; i < 4; i++) af[i] = *(const bf16x8*)&As[wr * 64 + i * 16 + l15][aoff];
#pragma unroll
    for (int j = 0; j < 4; j++) bfr[j] = *(const bf16x8*)&Bs[wc * 64 + j * 16 + l15][aoff];
#pragma unroll
    for (int i = 0; i < 4; i++)
#pragma unroll
      for (int j = 0; j < 4; j++)
        acc[i][j] = __builtin_amdgcn_mfma_f32_16x16x32_bf16(af[i], bfr[j], acc[i][j], 0, 0, 0);
  }
#pragma unroll
  for (int i = 0; i < 4; i++) {
#pragma unroll
    for (int j = 0; j < 4; j++) {
      int col = n0 + wc * 64 + j * 16 + l15;
#pragma unroll
      for (int r = 0; r < 4; r++) {
        int row = m0 + wr * 64 + i * 16 + q4 * 4 + r;
        float v = acc[i][j][r];
        if (EPI == 0) {
          if (col < 2 * HD) v = fmaxf(v, 0.f);
          outb[(size_t)row * Nc + col] = f2b(v);
        } else {
          outf[(size_t)row * Nc + col] = v + bias[col];
        }
      }
    }
  }
}

// kv[d][e] = sum_n k[n,d]*v[n,e] per (b,h); stored transposed kvT[bh][e*32+d]. Also ksum[bh][d].
// grid = 144*8 (8-way split over n), 64 threads; thread owns 4d x 4e outputs.
__global__ __launch_bounds__(64)
void kv_kernel(const uint16_t* __restrict__ qkvb, float* __restrict__ kvT, float* __restrict__ ksum) {
  __shared__ float kb[32][40];
  __shared__ float vb[32][40];
  const int bh = blockIdx.x >> 3;
  const int sp = blockIdx.x & 7;
  const int b = bh / HH, h = bh % HH;
  const int t = threadIdx.x;
  const int d0 = (t >> 3) * 4, e0 = (t & 7) * 4;
  const int m0 = b * NN + sp * (NN / 8);
  const size_t koff = (size_t)HD + h * DD;
  const size_t voff = (size_t)2 * HD + h * DD;
  float acc[4][4] = {};
  float ks[4] = {};
  const int srow = t >> 1, sseg = (t & 1) * 16;
  for (int c = 0; c < NN / 8; c += 32) {
    const uint16_t* kp = qkvb + (size_t)(m0 + c + srow) * N1 + koff + sseg;
    const uint16_t* vp = qkvb + (size_t)(m0 + c + srow) * N1 + voff + sseg;
    uint4 kr0 = *(const uint4*)kp;
    uint4 kr1 = *(const uint4*)(kp + 8);
    uint4 vr0 = *(const uint4*)vp;
    uint4 vr1 = *(const uint4*)(vp + 8);
    f32x4 klo, khi, klo2, khi2, vlo, vhi, vlo2, vhi2;
    unpack8v(kr0, klo, khi); unpack8v(kr1, klo2, khi2);
    unpack8v(vr0, vlo, vhi); unpack8v(vr1, vlo2, vhi2);
    __syncthreads();
    *(f32x4*)&kb[srow][sseg + 0] = klo;  *(f32x4*)&kb[srow][sseg + 4] = khi;
    *(f32x4*)&kb[srow][sseg + 8] = klo2; *(f32x4*)&kb[srow][sseg + 12] = khi2;
    *(f32x4*)&vb[srow][sseg + 0] = vlo;  *(f32x4*)&vb[srow][sseg + 4] = vhi;
    *(f32x4*)&vb[srow][sseg + 8] = vlo2; *(f32x4*)&vb[srow][sseg + 12] = vhi2;
    __syncthreads();
#pragma unroll 8
    for (int n = 0; n < 32; n++) {
      f32x4 kd = *(const f32x4*)&kb[n][d0];
      f32x4 ve = *(const f32x4*)&vb[n][e0];
#pragma unroll
      for (int i = 0; i < 4; i++)
#pragma unroll
        for (int j = 0; j < 4; j++) acc[i][j] += kd[i] * ve[j];
      if ((t & 7) == 0) {
#pragma unroll
        for (int i = 0; i < 4; i++) ks[i] += kd[i];
      }
    }
  }
#pragma unroll
  for (int i = 0; i < 4; i++)
#pragma unroll
    for (int j = 0; j < 4; j++)
      atomicAdd(&kvT[(size_t)bh * 1024 + (e0 + j) * DD + d0 + i], acc[i][j]);
  if ((t & 7) == 0) {
#pragma unroll
    for (int i = 0; i < 4; i++) atomicAdd(&ksum[bh * DD + d0 + i], ks[i]);
  }
}

// attn[m][h*32+e] = (sum_d q*kv[d][e]) / (sum_d q*ksum[d] + 1e-6), bf16 out.
// wave: lane = (dh:1)(e:5); kv column register-resident; 64 rows per wave.
__global__ __launch_bounds__(256)
void attn_kernel(const uint16_t* __restrict__ qkvb, const float* __restrict__ kvT,
                 const float* __restrict__ ksum, uint16_t* __restrict__ attn) {
  const int t = threadIdx.x;
  const int lane = t & 63, w = t >> 6;
  const int mbase = blockIdx.x * 256 + w * 64;
  const int b = mbase >> 13;
  const int e = lane & 31, dh = lane >> 5;
  const int h0 = blockIdx.y * HPB;
  for (int hh = 0; hh < HPB; hh++) {
    const int h = h0 + hh;
    const int bh = b * HH + h;
    const float* kvp = kvT + (size_t)bh * 1024 + e * DD + dh * 16;
    f32x4 kva = *(const f32x4*)(kvp + 0);
    f32x4 kvb2 = *(const f32x4*)(kvp + 4);
    f32x4 kvc = *(const f32x4*)(kvp + 8);
    f32x4 kvd = *(const f32x4*)(kvp + 12);
    const float* ksp = ksum + bh * DD + dh * 16;
    f32x4 ksa = *(const f32x4*)(ksp + 0);
    f32x4 ksb = *(const f32x4*)(ksp + 4);
    f32x4 ksc = *(const f32x4*)(ksp + 8);
    f32x4 ksd = *(const f32x4*)(ksp + 12);
#pragma unroll 4
    for (int r = 0; r < 64; r++) {
      const int m = mbase + r;
      const uint16_t* qp = qkvb + (size_t)m * N1 + h * DD + dh * 16;
      uint4 q0 = *(const uint4*)qp;
      uint4 q1 = *(const uint4*)(qp + 8);
      f32x4 qa, qb2, qc, qd;
      unpack8v(q0, qa, qb2);
      unpack8v(q1, qc, qd);
      float o = 0.f, den = 0.f;
#pragma unroll
      for (int ii = 0; ii < 4; ii++) {
        o += qa[ii] * kva[ii];  den += qa[ii] * ksa[ii];
        o += qb2[ii] * kvb2[ii]; den += qb2[ii] * ksb[ii];
        o += qc[ii] * kvc[ii];  den += qc[ii] * ksc[ii];
        o += qd[ii] * kvd[ii];  den += qd[ii] * ksd[ii];
      }
      o += __shfl_xor(o, 32);
      den += __shfl_xor(den, 32);
      float res = o / (den + 1e-6f);
      if (dh == 0) attn[(size_t)m * HD + h * DD + e] = f2b(res);
    }
  }
}

extern "C" void kernel_launch(void* const* d_in, const int* in_sizes, int n_in,
                              void* d_out, int out_size, void* d_ws, size_t ws_size,
                              hipStream_t stream) {
  const float* x = (const float*)d_in[0];
  const float* Wqkv = (const float*)d_in[1];
  const float* Wout = (const float*)d_in[2];
  const float* bout = (const float*)d_in[3];
  float* y = (float*)d_out;
  char* ws = (char*)d_ws;
  // workspace layout (bytes): xb/attn 75497472 | wqkvT 7962624 | woutT 2654208 |
  //                           qkvb 226492416 | kvT 589824 | ksum 18432   total 313214976
  uint16_t* xb = (uint16_t*)ws;
  uint16_t* wqkvT = (uint16_t*)(ws + 75497472);
  uint16_t* woutT = (uint16_t*)(ws + 83460096);
  uint16_t* qkvb = (uint16_t*)(ws + 86114304);
  float* kvT = (float*)(ws + 312606720);
  float* ksum = (float*)(ws + 313196544);
  uint16_t* attn = xb;  // alias: xb dead after GEMM1

  zero_kernel<<<(152064 + 255) / 256, 256, 0, stream>>>(kvT, 152064);  // kvT+ksum contiguous
  convert_kernel<<<(M_TOT * CC / 4) / 256, 256, 0, stream>>>(x, xb, M_TOT * CC / 4);
  transpose_convert_kernel<<<dim3(N1 / 32, CC / 32), 256, 0, stream>>>(Wqkv, wqkvT, CC, N1);
  transpose_convert_kernel<<<dim3(CC / 32, CC / 32), 256, 0, stream>>>(Wout, woutT, CC, CC);
  gemm_bf16_kernel<0><<<dim3(N1 / 128, M_TOT / 128), 256, 0, stream>>>(xb, wqkvT, qkvb, nullptr, nullptr, N1, CC);
  kv_kernel<<<144 * 8, 64, 0, stream>>>(qkvb, kvT, ksum);
  attn_kernel<<<dim3(M_TOT / 256, HH / HPB), 256, 0, stream>>>(qkvb, kvT, ksum, attn);
  gemm_bf16_kernel<1><<<dim3(CC / 128, M_TOT / 128), 256, 0, stream>>>(attn, woutT, nullptr, y, bout, CC, CC);
}

// Round 2
// 1033.324 us; speedup vs baseline: 1.1575x; 1.1575x over previous
//
#include <hip/hip_runtime.h>
#include <hip/hip_bf16.h>
#include <stdint.h>

// LinearAttention: B=4 N=8192 C=1152 H=36 D=32
// Pipeline: convert->bf16, GEMM1(qkv,+ReLU), kv-reduce, attn-normalize, GEMM2(+bias)
// R2: GEMMs moved to m97 structure (global_load_lds width-16, unpadded 128x32 LDS,
//     2-barrier K-loop) + XCD-aware block swizzle (n-fast within XCD-owned M-band).

#define HH 36
#define DD 32
#define CC 1152
#define NB 4
#define NN 8192
#define M_TOT (NB * NN)   // 32768
#define N1 (3 * HH * DD)  // 3456
#define HD (HH * DD)      // 1152
#define HPB 6

typedef __attribute__((ext_vector_type(8))) short bf16x8;
typedef __attribute__((ext_vector_type(4))) float f32x4;

__device__ __forceinline__ uint16_t f2b(float f) {
  union { float f; uint32_t u; } v; v.f = f;
  uint32_t u = v.u;
  return (uint16_t)((u + 0x7fffu + ((u >> 16) & 1u)) >> 16);
}
__device__ __forceinline__ float uasf(uint32_t u) {
  union { uint32_t u; float f; } v; v.u = u; return v.f;
}
// unpack 8 packed bf16 (uint4) -> two f32x4
__device__ __forceinline__ void unpack8v(uint4 u, f32x4& lo, f32x4& hi) {
  lo[0] = uasf(u.x << 16); lo[1] = uasf(u.x & 0xffff0000u);
  lo[2] = uasf(u.y << 16); lo[3] = uasf(u.y & 0xffff0000u);
  hi[0] = uasf(u.z << 16); hi[1] = uasf(u.z & 0xffff0000u);
  hi[2] = uasf(u.w << 16); hi[3] = uasf(u.w & 0xffff0000u);
}

// async global->LDS, 16B per lane; lds dest must be wave-uniform base (+lane*16 implicit)
#define GLOAD16(g, l)                                                        \
  __builtin_amdgcn_global_load_lds(                                          \
      (const __attribute__((address_space(1))) void*)(g),                    \
      (__attribute__((address_space(3))) void*)(l), 16, 0, 0)

__global__ void zero_kernel(float* __restrict__ p, int n) {
  int i = blockIdx.x * blockDim.x + threadIdx.x;
  if (i < n) p[i] = 0.f;
}

__global__ void convert_kernel(const float* __restrict__ in, uint16_t* __restrict__ out, int n4) {
  int i = blockIdx.x * blockDim.x + threadIdx.x;
  if (i >= n4) return;
  float4 v = ((const float4*)in)[i];
  ushort4 o;
  o.x = f2b(v.x); o.y = f2b(v.y); o.z = f2b(v.z); o.w = f2b(v.w);
  ((ushort4*)out)[i] = o;
}

// in: [R][Cc] fp32 -> out: [Cc][R] bf16  (32x32 LDS tile transpose)
__global__ void transpose_convert_kernel(const float* __restrict__ in, uint16_t* __restrict__ out,
                                         int R, int Cc) {
  __shared__ uint16_t tile[32][33];
  int c0 = blockIdx.x * 32, r0 = blockIdx.y * 32;
  int tx = threadIdx.x & 31, ty = threadIdx.x >> 5;
#pragma unroll
  for (int i = 0; i < 4; i++) {
    int r = ty + i * 8;
    tile[r][tx] = f2b(in[(size_t)(r0 + r) * Cc + c0 + tx]);
  }
  __syncthreads();
#pragma unroll
  for (int i = 0; i < 4; i++) {
    int c = ty + i * 8;
    out[(size_t)(c0 + c) * R + r0 + tx] = tile[tx][c];
  }
}

// C[m][n] = sum_k A[m][k] * BT[n][k].  128x128 tile, BK=32, 4 waves (2x2), each 64x64.
// m97 staging: global_load_lds dwordx4 into unpadded [128][32] LDS, 2-barrier K-loop.
// XCD swizzle: flat%8 = xcd owns m-bands xcd, xcd+8, ...; n iterates fast within band.
// EPI==0: ReLU on cols < 2*HD, store bf16.  EPI==1: +bias, store fp32.
template <int EPI, int NC>
__global__ __launch_bounds__(256)
void gemm_bf16_kernel(const uint16_t* __restrict__ A, const uint16_t* __restrict__ BT,
                      uint16_t* __restrict__ outb, float* __restrict__ outf,
                      const float* __restrict__ bias, int K) {
  constexpr int NT = NC / 128;
  __shared__ uint16_t As[128 * 32];
  __shared__ uint16_t Bs[128 * 32];
  const int flat = blockIdx.y * NT + blockIdx.x;
  const int xcd = flat & 7;
  const int s = flat >> 3;
  const int n0 = (s % NT) * 128;
  const int m0 = ((s / NT) * 8 + xcd) * 128;
  const int t = threadIdx.x;
  const int lane = t & 63, w = t >> 6;
  const int wr = w >> 1, wc = w & 1;
  const int l15 = lane & 15, q4 = lane >> 4;
  f32x4 acc[4][4] = {};

  // staging pointers: issue i covers rows [i*64, i*64+64); wave w rows w*16..+15
  const int srow = w * 16 + (lane >> 2);
  const int sseg = (lane & 3) * 8;
  const uint16_t* Ag0 = A + (size_t)(m0 + srow) * K + sseg;
  const uint16_t* Ag1 = Ag0 + (size_t)64 * K;
  const uint16_t* Bg0 = BT + (size_t)(n0 + srow) * K + sseg;
  const uint16_t* Bg1 = Bg0 + (size_t)64 * K;
  uint16_t* lA0 = &As[(w * 16) * 32];
  uint16_t* lA1 = &As[(64 + w * 16) * 32];
  uint16_t* lB0 = &Bs[(w * 16) * 32];
  uint16_t* lB1 = &Bs[(64 + w * 16) * 32];
  const int aoff = q4 * 8;

  for (int k0 = 0; k0 < K; k0 += 32) {
    __syncthreads();  // protect LDS from overwrite while prior iter still reading
    GLOAD16(Ag0 + k0, lA0);
    GLOAD16(Ag1 + k0, lA1);
    GLOAD16(Bg0 + k0, lB0);
    GLOAD16(Bg1 + k0, lB1);
    __syncthreads();  // implicit vmcnt(0) drain -> LDS data valid
    bf16x8 af[4], bfr[4];
#pragma unroll
    for (int i = 0; i < 4; i++) af[i] = *(const bf16x8*)&As[(wr * 64 + i * 16 + l15) * 32 + aoff];
#pragma unroll
    for (int j = 0; j < 4; j++) bfr[j] = *(const bf16x8*)&Bs[(wc * 64 + j * 16 + l15) * 32 + aoff];
#pragma unroll
    for (int i = 0; i < 4; i++)
#pragma unroll
      for (int j = 0; j < 4; j++)
        acc[i][j] = __builtin_amdgcn_mfma_f32_16x16x32_bf16(af[i], bfr[j], acc[i][j], 0, 0, 0);
  }
#pragma unroll
  for (int i = 0; i < 4; i++) {
#pragma unroll
    for (int j = 0; j < 4; j++) {
      int col = n0 + wc * 64 + j * 16 + l15;
#pragma unroll
      for (int r = 0; r < 4; r++) {
        int row = m0 + wr * 64 + i * 16 + q4 * 4 + r;
        float v = acc[i][j][r];
        if (EPI == 0) {
          if (col < 2 * HD) v = fmaxf(v, 0.f);
          outb[(size_t)row * NC + col] = f2b(v);
        } else {
          outf[(size_t)row * NC + col] = v + bias[col];
        }
      }
    }
  }
}

// kv[d][e] = sum_n k[n,d]*v[n,e] per (b,h); stored transposed kvT[bh][e*32+d]. Also ksum[bh][d].
// grid = 144*8 (8-way split over n), 64 threads; thread owns 4d x 4e outputs.
__global__ __launch_bounds__(64)
void kv_kernel(const uint16_t* __restrict__ qkvb, float* __restrict__ kvT, float* __restrict__ ksum) {
  __shared__ float kb[32][40];
  __shared__ float vb[32][40];
  const int bh = blockIdx.x >> 3;
  const int sp = blockIdx.x & 7;
  const int b = bh / HH, h = bh % HH;
  const int t = threadIdx.x;
  const int d0 = (t >> 3) * 4, e0 = (t & 7) * 4;
  const int m0 = b * NN + sp * (NN / 8);
  const size_t koff = (size_t)HD + h * DD;
  const size_t voff = (size_t)2 * HD + h * DD;
  float acc[4][4] = {};
  float ks[4] = {};
  const int srow = t >> 1, sseg = (t & 1) * 16;
  for (int c = 0; c < NN / 8; c += 32) {
    const uint16_t* kp = qkvb + (size_t)(m0 + c + srow) * N1 + koff + sseg;
    const uint16_t* vp = qkvb + (size_t)(m0 + c + srow) * N1 + voff + sseg;
    uint4 kr0 = *(const uint4*)kp;
    uint4 kr1 = *(const uint4*)(kp + 8);
    uint4 vr0 = *(const uint4*)vp;
    uint4 vr1 = *(const uint4*)(vp + 8);
    f32x4 klo, khi, klo2, khi2, vlo, vhi, vlo2, vhi2;
    unpack8v(kr0, klo, khi); unpack8v(kr1, klo2, khi2);
    unpack8v(vr0, vlo, vhi); unpack8v(vr1, vlo2, vhi2);
    __syncthreads();
    *(f32x4*)&kb[srow][sseg + 0] = klo;  *(f32x4*)&kb[srow][sseg + 4] = khi;
    *(f32x4*)&kb[srow][sseg + 8] = klo2; *(f32x4*)&kb[srow][sseg + 12] = khi2;
    *(f32x4*)&vb[srow][sseg + 0] = vlo;  *(f32x4*)&vb[srow][sseg + 4] = vhi;
    *(f32x4*)&vb[srow][sseg + 8] = vlo2; *(f32x4*)&vb[srow][sseg + 12] = vhi2;
    __syncthreads();
#pragma unroll 8
    for (int n = 0; n < 32; n++) {
      f32x4 kd = *(const f32x4*)&kb[n][d0];
      f32x4 ve = *(const f32x4*)&vb[n][e0];
#pragma unroll
      for (int i = 0; i < 4; i++)
#pragma unroll
        for (int j = 0; j < 4; j++) acc[i][j] += kd[i] * ve[j];
      if ((t & 7) == 0) {
#pragma unroll
        for (int i = 0; i < 4; i++) ks[i] += kd[i];
      }
    }
  }
#pragma unroll
  for (int i = 0; i < 4; i++)
#pragma unroll
    for (int j = 0; j < 4; j++)
      atomicAdd(&kvT[(size_t)bh * 1024 + (e0 + j) * DD + d0 + i], acc[i][j]);
  if ((t & 7) == 0) {
#pragma unroll
    for (int i = 0; i < 4; i++) atomicAdd(&ksum[bh * DD + d0 + i], ks[i]);
  }
}

// attn[m][h*32+e] = (sum_d q*kv[d][e]) / (sum_d q*ksum[d] + 1e-6), bf16 out.
// wave: lane = (dh:1)(e:5); kv column register-resident; 64 rows per wave.
__global__ __launch_bounds__(256)
void attn_kernel(const uint16_t* __restrict__ qkvb, const float* __restrict__ kvT,
                 const float* __restrict__ ksum, uint16_t* __restrict__ attn) {
  const int t = threadIdx.x;
  const int lane = t & 63, w = t >> 6;
  const int mbase = blockIdx.x * 256 + w * 64;
  const int b = mbase >> 13;
  const int e = lane & 31, dh = lane >> 5;
  const int h0 = blockIdx.y * HPB;
  for (int hh = 0; hh < HPB; hh++) {
    const int h = h0 + hh;
    const int bh = b * HH + h;
    const float* kvp = kvT + (size_t)bh * 1024 + e * DD + dh * 16;
    f32x4 kva = *(const f32x4*)(kvp + 0);
    f32x4 kvb2 = *(const f32x4*)(kvp + 4);
    f32x4 kvc = *(const f32x4*)(kvp + 8);
    f32x4 kvd = *(const f32x4*)(kvp + 12);
    const float* ksp = ksum + bh * DD + dh * 16;
    f32x4 ksa = *(const f32x4*)(ksp + 0);
    f32x4 ksb = *(const f32x4*)(ksp + 4);
    f32x4 ksc = *(const f32x4*)(ksp + 8);
    f32x4 ksd = *(const f32x4*)(ksp + 12);
#pragma unroll 4
    for (int r = 0; r < 64; r++) {
      const int m = mbase + r;
      const uint16_t* qp = qkvb + (size_t)m * N1 + h * DD + dh * 16;
      uint4 q0 = *(const uint4*)qp;
      uint4 q1 = *(const uint4*)(qp + 8);
      f32x4 qa, qb2, qc, qd;
      unpack8v(q0, qa, qb2);
      unpack8v(q1, qc, qd);
      float o = 0.f, den = 0.f;
#pragma unroll
      for (int ii = 0; ii < 4; ii++) {
        o += qa[ii] * kva[ii];  den += qa[ii] * ksa[ii];
        o += qb2[ii] * kvb2[ii]; den += qb2[ii] * ksb[ii];
        o += qc[ii] * kvc[ii];  den += qc[ii] * ksc[ii];
        o += qd[ii] * kvd[ii];  den += qd[ii] * ksd[ii];
      }
      o += __shfl_xor(o, 32);
      den += __shfl_xor(den, 32);
      float res = o / (den + 1e-6f);
      if (dh == 0) attn[(size_t)m * HD + h * DD + e] = f2b(res);
    }
  }
}

extern "C" void kernel_launch(void* const* d_in, const int* in_sizes, int n_in,
                              void* d_out, int out_size, void* d_ws, size_t ws_size,
                              hipStream_t stream) {
  const float* x = (const float*)d_in[0];
  const float* Wqkv = (const float*)d_in[1];
  const float* Wout = (const float*)d_in[2];
  const float* bout = (const float*)d_in[3];
  float* y = (float*)d_out;
  char* ws = (char*)d_ws;
  // workspace layout (bytes): xb/attn 75497472 | wqkvT 7962624 | woutT 2654208 |
  //                           qkvb 226492416 | kvT 589824 | ksum 18432   total 313214976
  uint16_t* xb = (uint16_t*)ws;
  uint16_t* wqkvT = (uint16_t*)(ws + 75497472);
  uint16_t* woutT = (uint16_t*)(ws + 83460096);
  uint16_t* qkvb = (uint16_t*)(ws + 86114304);
  float* kvT = (float*)(ws + 312606720);
  float* ksum = (float*)(ws + 313196544);
  uint16_t* attn = xb;  // alias: xb dead after GEMM1

  zero_kernel<<<(152064 + 255) / 256, 256, 0, stream>>>(kvT, 152064);  // kvT+ksum contiguous
  convert_kernel<<<(M_TOT * CC / 4) / 256, 256, 0, stream>>>(x, xb, M_TOT * CC / 4);
  transpose_convert_kernel<<<dim3(N1 / 32, CC / 32), 256, 0, stream>>>(Wqkv, wqkvT, CC, N1);
  transpose_convert_kernel<<<dim3(CC / 32, CC / 32), 256, 0, stream>>>(Wout, woutT, CC, CC);
  gemm_bf16_kernel<0, N1><<<dim3(N1 / 128, M_TOT / 128), 256, 0, stream>>>(xb, wqkvT, qkvb, nullptr, nullptr, CC);
  kv_kernel<<<144 * 8, 64, 0, stream>>>(qkvb, kvT, ksum);
  attn_kernel<<<dim3(M_TOT / 256, HH / HPB), 256, 0, stream>>>(qkvb, kvT, ksum, attn);
  gemm_bf16_kernel<1, CC><<<dim3(CC / 128, M_TOT / 128), 256, 0, stream>>>(attn, woutT, nullptr, y, bout, CC);
}

// Round 3
// 957.707 us; speedup vs baseline: 1.2489x; 1.0790x over previous
//
#include <hip/hip_runtime.h>
#include <hip/hip_bf16.h>
#include <stdint.h>

// LinearAttention: B=4 N=8192 C=1152 H=36 D=32
// Pipeline: convert->bf16, GEMM1(qkv,+ReLU), kv-reduce, attn-normalize, GEMM2(+bias)
// R3: GEMM LDS XOR-swizzle (conflict-free frag reads under global_load_lds's
//     lane-contiguous scatter) + BK=64 (half the barrier drains, 32KB LDS,
//     launch_bounds(256,4) to hold 4 blocks/CU). kv split 8->32, attn HPB 6->3.

#define HH 36
#define DD 32
#define CC 1152
#define NB 4
#define NN 8192
#define M_TOT (NB * NN)   // 32768
#define N1 (3 * HH * DD)  // 3456
#define HD (HH * DD)      // 1152
#define HPB 3
#define KVSPLIT 32

typedef __attribute__((ext_vector_type(8))) short bf16x8;
typedef __attribute__((ext_vector_type(4))) float f32x4;

__device__ __forceinline__ uint16_t f2b(float f) {
  union { float f; uint32_t u; } v; v.f = f;
  uint32_t u = v.u;
  return (uint16_t)((u + 0x7fffu + ((u >> 16) & 1u)) >> 16);
}
__device__ __forceinline__ float uasf(uint32_t u) {
  union { uint32_t u; float f; } v; v.u = u; return v.f;
}
// unpack 8 packed bf16 (uint4) -> two f32x4
__device__ __forceinline__ void unpack8v(uint4 u, f32x4& lo, f32x4& hi) {
  lo[0] = uasf(u.x << 16); lo[1] = uasf(u.x & 0xffff0000u);
  lo[2] = uasf(u.y << 16); lo[3] = uasf(u.y & 0xffff0000u);
  hi[0] = uasf(u.z << 16); hi[1] = uasf(u.z & 0xffff0000u);
  hi[2] = uasf(u.w << 16); hi[3] = uasf(u.w & 0xffff0000u);
}

// async global->LDS, 16B per lane; lds dest is wave-uniform base (+lane*16 implicit)
#define GLOAD16(g, l)                                                        \
  __builtin_amdgcn_global_load_lds(                                          \
      (const __attribute__((address_space(1))) void*)(g),                    \
      (__attribute__((address_space(3))) void*)(l), 16, 0, 0)

__global__ void zero_kernel(float* __restrict__ p, int n) {
  int i = blockIdx.x * blockDim.x + threadIdx.x;
  if (i < n) p[i] = 0.f;
}

__global__ void convert_kernel(const float* __restrict__ in, uint16_t* __restrict__ out, int n4) {
  int i = blockIdx.x * blockDim.x + threadIdx.x;
  if (i >= n4) return;
  float4 v = ((const float4*)in)[i];
  ushort4 o;
  o.x = f2b(v.x); o.y = f2b(v.y); o.z = f2b(v.z); o.w = f2b(v.w);
  ((ushort4*)out)[i] = o;
}

// in: [R][Cc] fp32 -> out: [Cc][R] bf16  (32x32 LDS tile transpose)
__global__ void transpose_convert_kernel(const float* __restrict__ in, uint16_t* __restrict__ out,
                                         int R, int Cc) {
  __shared__ uint16_t tile[32][33];
  int c0 = blockIdx.x * 32, r0 = blockIdx.y * 32;
  int tx = threadIdx.x & 31, ty = threadIdx.x >> 5;
#pragma unroll
  for (int i = 0; i < 4; i++) {
    int r = ty + i * 8;
    tile[r][tx] = f2b(in[(size_t)(r0 + r) * Cc + c0 + tx]);
  }
  __syncthreads();
#pragma unroll
  for (int i = 0; i < 4; i++) {
    int c = ty + i * 8;
    out[(size_t)(c0 + c) * R + r0 + tx] = tile[tx][c];
  }
}

// C[m][n] = sum_k A[m][k] * BT[n][k].  128x128 tile, BK=64, 4 waves (2x2), each 64x64.
// LDS layout: row stride 64 elems (8 segs of 8 elems); physical seg p holds logical
// k-seg p^(row&7). Staging picks the global k-seg per lane so the HW's contiguous
// lane*16 scatter lands swizzled; fragment reads then hit all 32 banks per 8-lane
// group (conflict-free). XCD swizzle: flat%8 = xcd owns m-bands; n fast within band.
// EPI==0: ReLU on cols < 2*HD, store bf16.  EPI==1: +bias, store fp32.
template <int EPI, int NC>
__global__ __launch_bounds__(256, 4)
void gemm_bf16_kernel(const uint16_t* __restrict__ A, const uint16_t* __restrict__ BT,
                      uint16_t* __restrict__ outb, float* __restrict__ outf,
                      const float* __restrict__ bias, int K) {
  constexpr int NT = NC / 128;
  __shared__ uint16_t As[128 * 64];
  __shared__ uint16_t Bs[128 * 64];
  const int flat = blockIdx.y * NT + blockIdx.x;
  const int xcd = flat & 7;
  const int s = flat >> 3;
  const int n0 = (s % NT) * 128;
  const int m0 = ((s / NT) * 8 + xcd) * 128;
  const int t = threadIdx.x;
  const int lane = t & 63, w = t >> 6;
  const int wr = w >> 1, wc = w & 1;
  const int l15 = lane & 15, q4 = lane >> 4;
  f32x4 acc[4][4] = {};

  // staging: wave w covers rows [w*32, w*32+32) in 4 issues of 8 rows (1KB each).
  // lane -> (row = +lane/8, phys seg = lane&7); global k-seg = (lane&7)^(lane>>3).
  const int srow = w * 32 + (lane >> 3);
  const int sseg = ((lane & 7) ^ (lane >> 3)) * 8;
  const uint16_t* Ag = A + (size_t)(m0 + srow) * K + sseg;
  const uint16_t* Bg = BT + (size_t)(n0 + srow) * K + sseg;
  uint16_t* lA = &As[(w * 32) * 64];
  uint16_t* lB = &Bs[(w * 32) * 64];

  for (int k0 = 0; k0 < K; k0 += 64) {
    __syncthreads();  // protect LDS while prior iter still reading
#pragma unroll
    for (int i = 0; i < 4; i++) {
      GLOAD16(Ag + k0 + (size_t)(i * 8) * K, lA + i * 8 * 64);
      GLOAD16(Bg + k0 + (size_t)(i * 8) * K, lB + i * 8 * 64);
    }
    __syncthreads();  // vmcnt(0) drain -> LDS valid
#pragma unroll
    for (int kk = 0; kk < 2; kk++) {
      bf16x8 af[4], bfr[4];
      const int sbase = (kk * 4 + q4);
#pragma unroll
      for (int i = 0; i < 4; i++) {
        const int row = wr * 64 + i * 16 + l15;
        af[i] = *(const bf16x8*)&As[row * 64 + (sbase ^ (l15 & 7)) * 8];
      }
#pragma unroll
      for (int j = 0; j < 4; j++) {
        const int row = wc * 64 + j * 16 + l15;
        bfr[j] = *(const bf16x8*)&Bs[row * 64 + (sbase ^ (l15 & 7)) * 8];
      }
#pragma unroll
      for (int i = 0; i < 4; i++)
#pragma unroll
        for (int j = 0; j < 4; j++)
          acc[i][j] = __builtin_amdgcn_mfma_f32_16x16x32_bf16(af[i], bfr[j], acc[i][j], 0, 0, 0);
    }
  }
#pragma unroll
  for (int i = 0; i < 4; i++) {
#pragma unroll
    for (int j = 0; j < 4; j++) {
      int col = n0 + wc * 64 + j * 16 + l15;
#pragma unroll
      for (int r = 0; r < 4; r++) {
        int row = m0 + wr * 64 + i * 16 + q4 * 4 + r;
        float v = acc[i][j][r];
        if (EPI == 0) {
          if (col < 2 * HD) v = fmaxf(v, 0.f);
          outb[(size_t)row * NC + col] = f2b(v);
        } else {
          outf[(size_t)row * NC + col] = v + bias[col];
        }
      }
    }
  }
}

// kv[d][e] = sum_n k[n,d]*v[n,e] per (b,h); stored transposed kvT[bh][e*32+d]. Also ksum[bh][d].
// grid = 144*KVSPLIT (split over n), 64 threads; thread owns 4d x 4e outputs.
__global__ __launch_bounds__(64)
void kv_kernel(const uint16_t* __restrict__ qkvb, float* __restrict__ kvT, float* __restrict__ ksum) {
  __shared__ float kb[32][40];
  __shared__ float vb[32][40];
  const int bh = blockIdx.x / KVSPLIT;
  const int sp = blockIdx.x % KVSPLIT;
  const int b = bh / HH, h = bh % HH;
  const int t = threadIdx.x;
  const int d0 = (t >> 3) * 4, e0 = (t & 7) * 4;
  const int m0 = b * NN + sp * (NN / KVSPLIT);
  const size_t koff = (size_t)HD + h * DD;
  const size_t voff = (size_t)2 * HD + h * DD;
  float acc[4][4] = {};
  float ks[4] = {};
  const int srow = t >> 1, sseg = (t & 1) * 16;
  for (int c = 0; c < NN / KVSPLIT; c += 32) {
    const uint16_t* kp = qkvb + (size_t)(m0 + c + srow) * N1 + koff + sseg;
    const uint16_t* vp = qkvb + (size_t)(m0 + c + srow) * N1 + voff + sseg;
    uint4 kr0 = *(const uint4*)kp;
    uint4 kr1 = *(const uint4*)(kp + 8);
    uint4 vr0 = *(const uint4*)vp;
    uint4 vr1 = *(const uint4*)(vp + 8);
    f32x4 klo, khi, klo2, khi2, vlo, vhi, vlo2, vhi2;
    unpack8v(kr0, klo, khi); unpack8v(kr1, klo2, khi2);
    unpack8v(vr0, vlo, vhi); unpack8v(vr1, vlo2, vhi2);
    __syncthreads();
    *(f32x4*)&kb[srow][sseg + 0] = klo;  *(f32x4*)&kb[srow][sseg + 4] = khi;
    *(f32x4*)&kb[srow][sseg + 8] = klo2; *(f32x4*)&kb[srow][sseg + 12] = khi2;
    *(f32x4*)&vb[srow][sseg + 0] = vlo;  *(f32x4*)&vb[srow][sseg + 4] = vhi;
    *(f32x4*)&vb[srow][sseg + 8] = vlo2; *(f32x4*)&vb[srow][sseg + 12] = vhi2;
    __syncthreads();
#pragma unroll 8
    for (int n = 0; n < 32; n++) {
      f32x4 kd = *(const f32x4*)&kb[n][d0];
      f32x4 ve = *(const f32x4*)&vb[n][e0];
#pragma unroll
      for (int i = 0; i < 4; i++)
#pragma unroll
        for (int j = 0; j < 4; j++) acc[i][j] += kd[i] * ve[j];
      if ((t & 7) == 0) {
#pragma unroll
        for (int i = 0; i < 4; i++) ks[i] += kd[i];
      }
    }
  }
#pragma unroll
  for (int i = 0; i < 4; i++)
#pragma unroll
    for (int j = 0; j < 4; j++)
      atomicAdd(&kvT[(size_t)bh * 1024 + (e0 + j) * DD + d0 + i], acc[i][j]);
  if ((t & 7) == 0) {
#pragma unroll
    for (int i = 0; i < 4; i++) atomicAdd(&ksum[bh * DD + d0 + i], ks[i]);
  }
}

// attn[m][h*32+e] = (sum_d q*kv[d][e]) / (sum_d q*ksum[d] + 1e-6), bf16 out.
// wave: lane = (dh:1)(e:5); kv column register-resident; 64 rows per wave.
__global__ __launch_bounds__(256)
void attn_kernel(const uint16_t* __restrict__ qkvb, const float* __restrict__ kvT,
                 const float* __restrict__ ksum, uint16_t* __restrict__ attn) {
  const int t = threadIdx.x;
  const int lane = t & 63, w = t >> 6;
  const int mbase = blockIdx.x * 256 + w * 64;
  const int b = mbase >> 13;
  const int e = lane & 31, dh = lane >> 5;
  const int h0 = blockIdx.y * HPB;
  for (int hh = 0; hh < HPB; hh++) {
    const int h = h0 + hh;
    const int bh = b * HH + h;
    const float* kvp = kvT + (size_t)bh * 1024 + e * DD + dh * 16;
    f32x4 kva = *(const f32x4*)(kvp + 0);
    f32x4 kvb2 = *(const f32x4*)(kvp + 4);
    f32x4 kvc = *(const f32x4*)(kvp + 8);
    f32x4 kvd = *(const f32x4*)(kvp + 12);
    const float* ksp = ksum + bh * DD + dh * 16;
    f32x4 ksa = *(const f32x4*)(ksp + 0);
    f32x4 ksb = *(const f32x4*)(ksp + 4);
    f32x4 ksc = *(const f32x4*)(ksp + 8);
    f32x4 ksd = *(const f32x4*)(ksp + 12);
#pragma unroll 4
    for (int r = 0; r < 64; r++) {
      const int m = mbase + r;
      const uint16_t* qp = qkvb + (size_t)m * N1 + h * DD + dh * 16;
      uint4 q0 = *(const uint4*)qp;
      uint4 q1 = *(const uint4*)(qp + 8);
      f32x4 qa, qb2, qc, qd;
      unpack8v(q0, qa, qb2);
      unpack8v(q1, qc, qd);
      float o = 0.f, den = 0.f;
#pragma unroll
      for (int ii = 0; ii < 4; ii++) {
        o += qa[ii] * kva[ii];  den += qa[ii] * ksa[ii];
        o += qb2[ii] * kvb2[ii]; den += qb2[ii] * ksb[ii];
        o += qc[ii] * kvc[ii];  den += qc[ii] * ksc[ii];
        o += qd[ii] * kvd[ii];  den += qd[ii] * ksd[ii];
      }
      o += __shfl_xor(o, 32);
      den += __shfl_xor(den, 32);
      float res = o / (den + 1e-6f);
      if (dh == 0) attn[(size_t)m * HD + h * DD + e] = f2b(res);
    }
  }
}

extern "C" void kernel_launch(void* const* d_in, const int* in_sizes, int n_in,
                              void* d_out, int out_size, void* d_ws, size_t ws_size,
                              hipStream_t stream) {
  const float* x = (const float*)d_in[0];
  const float* Wqkv = (const float*)d_in[1];
  const float* Wout = (const float*)d_in[2];
  const float* bout = (const float*)d_in[3];
  float* y = (float*)d_out;
  char* ws = (char*)d_ws;
  // workspace layout (bytes): xb/attn 75497472 | wqkvT 7962624 | woutT 2654208 |
  //                           qkvb 226492416 | kvT 589824 | ksum 18432   total 313214976
  uint16_t* xb = (uint16_t*)ws;
  uint16_t* wqkvT = (uint16_t*)(ws + 75497472);
  uint16_t* woutT = (uint16_t*)(ws + 83460096);
  uint16_t* qkvb = (uint16_t*)(ws + 86114304);
  float* kvT = (float*)(ws + 312606720);
  float* ksum = (float*)(ws + 313196544);
  uint16_t* attn = xb;  // alias: xb dead after GEMM1

  zero_kernel<<<(152064 + 255) / 256, 256, 0, stream>>>(kvT, 152064);  // kvT+ksum contiguous
  convert_kernel<<<(M_TOT * CC / 4) / 256, 256, 0, stream>>>(x, xb, M_TOT * CC / 4);
  transpose_convert_kernel<<<dim3(N1 / 32, CC / 32), 256, 0, stream>>>(Wqkv, wqkvT, CC, N1);
  transpose_convert_kernel<<<dim3(CC / 32, CC / 32), 256, 0, stream>>>(Wout, woutT, CC, CC);
  gemm_bf16_kernel<0, N1><<<dim3(N1 / 128, M_TOT / 128), 256, 0, stream>>>(xb, wqkvT, qkvb, nullptr, nullptr, CC);
  kv_kernel<<<144 * KVSPLIT, 64, 0, stream>>>(qkvb, kvT, ksum);
  attn_kernel<<<dim3(M_TOT / 256, HH / HPB), 256, 0, stream>>>(qkvb, kvT, ksum, attn);
  gemm_bf16_kernel<1, CC><<<dim3(CC / 128, M_TOT / 128), 256, 0, stream>>>(attn, woutT, nullptr, y, bout, CC);
}